// Round 1
// baseline (709.175 us; speedup 1.0000x reference)
//
#include <hip/hip_runtime.h>
#include <math.h>

#define NS   768
#define DIM  512
#define NH   8
#define HD   64
#define BD   40
#define HBD  320
#define NROWS (768*768)

// ---------------------------------------------------------------------------
// GEMM: C[768][512] = A[768][512] @ W[512][512]^T + b, optional mish
// block 256 threads, 64x64 tile, BK=32, thread computes 4x4
// ---------------------------------------------------------------------------
__global__ __launch_bounds__(256) void gemm_tn(const float* __restrict__ A,
                                               const float* __restrict__ W,
                                               const float* __restrict__ bvec,
                                               float* __restrict__ C,
                                               int act)
{
    __shared__ float As[32][68];
    __shared__ float Ws[32][68];
    const int t  = threadIdx.x;
    const int m0 = blockIdx.x * 64;
    const int cb = blockIdx.y * 64;
    const int r0 = (t >> 4) * 4;
    const int c0 = (t & 15) * 4;

    float acc[4][4];
#pragma unroll
    for (int i = 0; i < 4; ++i)
#pragma unroll
        for (int j = 0; j < 4; ++j) acc[i][j] = 0.f;

    for (int k0 = 0; k0 < DIM; k0 += 32) {
        __syncthreads();
#pragma unroll
        for (int l = 0; l < 8; ++l) {
            int idx = t + l * 256;
            int r = idx >> 5, kk = idx & 31;
            As[kk][r] = A[(size_t)(m0 + r) * DIM + k0 + kk];
            Ws[kk][r] = W[(size_t)(cb + r) * DIM + k0 + kk];
        }
        __syncthreads();
#pragma unroll
        for (int kk = 0; kk < 32; ++kk) {
            float4 av = *(const float4*)&As[kk][r0];
            float4 bv = *(const float4*)&Ws[kk][c0];
            float a[4] = {av.x, av.y, av.z, av.w};
            float b[4] = {bv.x, bv.y, bv.z, bv.w};
#pragma unroll
            for (int i = 0; i < 4; ++i)
#pragma unroll
                for (int j = 0; j < 4; ++j)
                    acc[i][j] += a[i] * b[j];
        }
    }
#pragma unroll
    for (int i = 0; i < 4; ++i) {
        float o[4];
#pragma unroll
        for (int j = 0; j < 4; ++j) {
            float x = acc[i][j] + bvec[cb + c0 + j];
            if (act) x = x * tanhf(log1pf(expf(x)));
            o[j] = x;
        }
        *(float4*)&C[(size_t)(m0 + r0 + i) * DIM + cb + c0] =
            make_float4(o[0], o[1], o[2], o[3]);
    }
}

// ---------------------------------------------------------------------------
// bias_p = bias @ bp_w^T + bp_b  (rows = 589824, K=40, N=320), fused diffs:
// diffs[chunk] = ||bias_p_flat[chunk*40 .. +40)||_2, chunk = row*8 + c/40
// block: 256 thr, 64 rows; thread: 4 rows x 20 cols register tile
// ---------------------------------------------------------------------------
__global__ __launch_bounds__(256) void biasp_diffs(const float* __restrict__ bias,
                                                   const float* __restrict__ bp_w,
                                                   const float* __restrict__ bp_b,
                                                   float* __restrict__ bias_p,
                                                   float* __restrict__ diffs)
{
    __shared__ float wT[BD][HBD + 4];   // [k][c], stride 324 (16B aligned)
    __shared__ float rT[BD][68];        // [k][r]
    __shared__ float bsh[HBD];

    const int  t    = threadIdx.x;
    const long row0 = (long)blockIdx.x * 64;

    for (int idx = t; idx < HBD * BD; idx += 256) {
        int c = idx / BD, k = idx - c * BD;
        wT[k][c] = bp_w[idx];
    }
    for (int idx = t; idx < HBD; idx += 256) bsh[idx] = bp_b[idx];
    for (int idx = t; idx < 64 * BD; idx += 256) {
        int r = idx / BD, k = idx - r * BD;
        rT[k][r] = bias[row0 * BD + idx];
    }
    __syncthreads();

    const int rg = t >> 4;          // 0..15
    const int cg = t & 15;          // 0..15
    const int rb = rg * 4;          // row base
    const int c0 = cg * 20;         // col base (20 | 40 -> no chunk straddle)

    float acc[4][20];
#pragma unroll
    for (int i = 0; i < 4; ++i)
#pragma unroll
        for (int j = 0; j < 20; ++j) acc[i][j] = 0.f;

    for (int k = 0; k < BD; ++k) {
        float4 r4 = *(const float4*)&rT[k][rb];
        float rv[4] = {r4.x, r4.y, r4.z, r4.w};
        float wv[20];
#pragma unroll
        for (int j = 0; j < 20; j += 4) {
            float4 w4 = *(const float4*)&wT[k][c0 + j];
            wv[j] = w4.x; wv[j+1] = w4.y; wv[j+2] = w4.z; wv[j+3] = w4.w;
        }
#pragma unroll
        for (int i = 0; i < 4; ++i)
#pragma unroll
            for (int j = 0; j < 20; ++j)
                acc[i][j] += rv[i] * wv[j];
    }

#pragma unroll
    for (int i = 0; i < 4; ++i) {
        const long row = row0 + rb + i;
        float s = 0.f;
        float o[20];
#pragma unroll
        for (int j = 0; j < 20; ++j) {
            float x = acc[i][j] + bsh[c0 + j];
            o[j] = x;
            s += x * x;
        }
#pragma unroll
        for (int j = 0; j < 20; j += 4)
            *(float4*)&bias_p[row * HBD + c0 + j] =
                make_float4(o[j], o[j+1], o[j+2], o[j+3]);
        s += __shfl_xor(s, 1);
        if ((cg & 1) == 0) diffs[row * 8 + (cg >> 1)] = sqrtf(s);
    }
}

// ---------------------------------------------------------------------------
// attention: per (head, 16-row q tile): logits = qh.kh^T/8 + diffs,
// softmax over M=768 (in LDS), then PV.  vals[n][h*64+d]
// ---------------------------------------------------------------------------
__global__ __launch_bounds__(256) void attn_kernel(const float* __restrict__ Qp,
                                                   const float* __restrict__ Kp,
                                                   const float* __restrict__ Vp,
                                                   const float* __restrict__ diffs,
                                                   float* __restrict__ vals)
{
    __shared__ float Ql[16][68];
    __shared__ float KV[64 * 68];       // K phase: [d][mm] stride 65; V: [mm][d] stride 68
    __shared__ float L[16 * 769];
    __shared__ float red[16][17];
    __shared__ float rowmax[16], rowsuminv[16];

    const int t  = threadIdx.x;
    const int h  = blockIdx.y;
    const int n0 = blockIdx.x * 16;

    for (int idx = t; idx < 16 * 64; idx += 256) {
        int r = idx >> 6, d = idx & 63;
        Ql[r][d] = Qp[(size_t)(n0 + r) * DIM + h * HD + d];
    }

    const int wv  = t >> 6;     // wave id: rows {wv, wv+4, wv+8, wv+12}
    const int mmq = t & 63;

    // ---- phase 1: logits ----
    for (int mt = 0; mt < 12; ++mt) {
        __syncthreads();
        for (int idx = t; idx < 64 * 64; idx += 256) {
            int mm = idx >> 6, d = idx & 63;
            KV[d * 65 + mm] = Kp[(size_t)(mt * 64 + mm) * DIM + h * HD + d];
        }
        __syncthreads();
        float a0 = 0, a1 = 0, a2 = 0, a3 = 0;
#pragma unroll
        for (int d = 0; d < 64; d += 4) {
            float4 q0 = *(const float4*)&Ql[wv][d];
            float4 q1 = *(const float4*)&Ql[wv + 4][d];
            float4 q2 = *(const float4*)&Ql[wv + 8][d];
            float4 q3 = *(const float4*)&Ql[wv + 12][d];
            float k0 = KV[(d    ) * 65 + mmq];
            float k1 = KV[(d + 1) * 65 + mmq];
            float k2 = KV[(d + 2) * 65 + mmq];
            float k3 = KV[(d + 3) * 65 + mmq];
            a0 += q0.x * k0 + q0.y * k1 + q0.z * k2 + q0.w * k3;
            a1 += q1.x * k0 + q1.y * k1 + q1.z * k2 + q1.w * k3;
            a2 += q2.x * k0 + q2.y * k1 + q2.z * k2 + q2.w * k3;
            a3 += q3.x * k0 + q3.y * k1 + q3.z * k2 + q3.w * k3;
        }
        const int m = mt * 64 + mmq;
        const size_t db = (size_t)h * (768 * 768) + (size_t)n0 * 768;
        L[(wv     ) * 769 + m] = a0 * 0.125f + diffs[db + (size_t)(wv     ) * 768 + m];
        L[(wv +  4) * 769 + m] = a1 * 0.125f + diffs[db + (size_t)(wv +  4) * 768 + m];
        L[(wv +  8) * 769 + m] = a2 * 0.125f + diffs[db + (size_t)(wv +  8) * 768 + m];
        L[(wv + 12) * 769 + m] = a3 * 0.125f + diffs[db + (size_t)(wv + 12) * 768 + m];
    }
    __syncthreads();

    // ---- phase 2: softmax over 768 per row ----
    {
        const int r = t & 15, seg = t >> 4;
        float mx = -3.4e38f;
        for (int j = 0; j < 48; ++j) mx = fmaxf(mx, L[r * 769 + seg * 48 + j]);
        red[r][seg] = mx;
        __syncthreads();
        if (t < 16) {
            float m = red[t][0];
            for (int s2 = 1; s2 < 16; ++s2) m = fmaxf(m, red[t][s2]);
            rowmax[t] = m;
        }
        __syncthreads();
        const float m = rowmax[r];
        float s = 0.f;
        for (int j = 0; j < 48; ++j) {
            float e = __expf(L[r * 769 + seg * 48 + j] - m);
            L[r * 769 + seg * 48 + j] = e;
            s += e;
        }
        red[r][seg] = s;
        __syncthreads();
        if (t < 16) {
            float sm = 0.f;
            for (int s2 = 0; s2 < 16; ++s2) sm += red[t][s2];
            rowsuminv[t] = 1.f / sm;
        }
    }

    // ---- phase 3: PV ----
    const int r3 = t >> 4, dq = t & 15;
    float4 acc = make_float4(0, 0, 0, 0);
    for (int mt = 0; mt < 12; ++mt) {
        __syncthreads();
        for (int idx = t; idx < 64 * 64; idx += 256) {
            int mm = idx >> 6, d = idx & 63;
            KV[mm * 68 + d] = Vp[(size_t)(mt * 64 + mm) * DIM + h * HD + d];
        }
        __syncthreads();
#pragma unroll 8
        for (int m = 0; m < 64; ++m) {
            float p = L[r3 * 769 + mt * 64 + m];
            float4 vv = *(const float4*)&KV[m * 68 + dq * 4];
            acc.x += p * vv.x; acc.y += p * vv.y;
            acc.z += p * vv.z; acc.w += p * vv.w;
        }
    }
    const float inv = rowsuminv[r3];
    acc.x *= inv; acc.y *= inv; acc.z *= inv; acc.w *= inv;
    *(float4*)&vals[(size_t)(n0 + r3) * DIM + h * HD + dq * 4] = acc;
}

// ---------------------------------------------------------------------------
extern "C" void kernel_launch(void* const* d_in, const int* in_sizes, int n_in,
                              void* d_out, int out_size, void* d_ws, size_t ws_size,
                              hipStream_t stream)
{
    const float* q    = (const float*)d_in[0];
    const float* k    = (const float*)d_in[1];
    const float* v    = (const float*)d_in[2];
    const float* bias = (const float*)d_in[3];
    const float* q_w  = (const float*)d_in[4];
    const float* q_b  = (const float*)d_in[5];
    const float* k_w  = (const float*)d_in[6];
    const float* k_b  = (const float*)d_in[7];
    const float* v_w  = (const float*)d_in[8];
    const float* v_b  = (const float*)d_in[9];
    const float* bp_w = (const float*)d_in[10];
    const float* bp_b = (const float*)d_in[11];
    const float* o1_w = (const float*)d_in[12];
    const float* o1_b = (const float*)d_in[13];
    const float* o2_w = (const float*)d_in[14];
    const float* o2_b = (const float*)d_in[15];

    float* out    = (float*)d_out;                 // [768][512]
    float* bias_p = (float*)d_out + 393216;        // [589824][320]

    float* ws    = (float*)d_ws;
    float* Qp    = ws;                 // 768*512
    float* Kp    = ws + 393216;
    float* Vp    = ws + 786432;
    float* vals  = ws + 1179648;
    float* mid   = ws + 1572864;
    float* diffs = ws + 1966080;       // 8*768*768

    dim3 gg(12, 8), gb(256);
    gemm_tn<<<gg, gb, 0, stream>>>(q, q_w, q_b, Qp, 0);
    gemm_tn<<<gg, gb, 0, stream>>>(k, k_w, k_b, Kp, 0);
    gemm_tn<<<gg, gb, 0, stream>>>(v, v_w, v_b, Vp, 0);
    biasp_diffs<<<dim3(NROWS / 64), gb, 0, stream>>>(bias, bp_w, bp_b, bias_p, diffs);
    attn_kernel<<<dim3(48, NH), gb, 0, stream>>>(Qp, Kp, Vp, diffs, vals);
    gemm_tn<<<gg, gb, 0, stream>>>(vals, o1_w, o1_b, mid, 1);
    gemm_tn<<<gg, gb, 0, stream>>>(mid, o2_w, o2_b, out, 0);
}

// Round 2
// 490.934 us; speedup vs baseline: 1.4445x; 1.4445x over previous
//
#include <hip/hip_runtime.h>
#include <math.h>

#define NS   768
#define DIM  512
#define NH   8
#define HD   64
#define BD   40
#define HBD  320
#define NROWS (768*768)

typedef __bf16 bf16x8 __attribute__((ext_vector_type(8)));
typedef float  f32x4  __attribute__((ext_vector_type(4)));

union FragU {
    bf16x8 v;
    unsigned short u[8];
    uint2 d2[2];
};

__device__ inline unsigned short f2bf(float f) {
    unsigned int u = __float_as_uint(f);
    unsigned int r = (u + 0x7fffu + ((u >> 16) & 1u)) >> 16;
    return (unsigned short)r;
}

// ---------------------------------------------------------------------------
// GEMM: C[768][512] = A[768][512] @ W[512][512]^T + b, optional mish
// ---------------------------------------------------------------------------
__global__ __launch_bounds__(256) void gemm_tn(const float* __restrict__ A,
                                               const float* __restrict__ W,
                                               const float* __restrict__ bvec,
                                               float* __restrict__ C,
                                               int act)
{
    __shared__ float As[32][68];
    __shared__ float Ws[32][68];
    const int t  = threadIdx.x;
    const int m0 = blockIdx.x * 64;
    const int cb = blockIdx.y * 64;
    const int r0 = (t >> 4) * 4;
    const int c0 = (t & 15) * 4;

    float acc[4][4];
#pragma unroll
    for (int i = 0; i < 4; ++i)
#pragma unroll
        for (int j = 0; j < 4; ++j) acc[i][j] = 0.f;

    for (int k0 = 0; k0 < DIM; k0 += 32) {
        __syncthreads();
#pragma unroll
        for (int l = 0; l < 8; ++l) {
            int idx = t + l * 256;
            int r = idx >> 5, kk = idx & 31;
            As[kk][r] = A[(size_t)(m0 + r) * DIM + k0 + kk];
            Ws[kk][r] = W[(size_t)(cb + r) * DIM + k0 + kk];
        }
        __syncthreads();
#pragma unroll
        for (int kk = 0; kk < 32; ++kk) {
            float4 av = *(const float4*)&As[kk][r0];
            float4 bv = *(const float4*)&Ws[kk][c0];
            float a[4] = {av.x, av.y, av.z, av.w};
            float b[4] = {bv.x, bv.y, bv.z, bv.w};
#pragma unroll
            for (int i = 0; i < 4; ++i)
#pragma unroll
                for (int j = 0; j < 4; ++j)
                    acc[i][j] += a[i] * b[j];
        }
    }
#pragma unroll
    for (int i = 0; i < 4; ++i) {
        float o[4];
#pragma unroll
        for (int j = 0; j < 4; ++j) {
            float x = acc[i][j] + bvec[cb + c0 + j];
            if (act) x = x * tanhf(log1pf(expf(x)));
            o[j] = x;
        }
        *(float4*)&C[(size_t)(m0 + r0 + i) * DIM + cb + c0] =
            make_float4(o[0], o[1], o[2], o[3]);
    }
}

// ---------------------------------------------------------------------------
// biasp_diffs via MFMA bf16:
//   bias_p[r][c] = sum_k bias[r][k] * bp_w[c][k] + bp_b[c]   (r<589824, c<320, k<40)
//   diffs[r*8 + c/40] = L2 norm of 40-chunk
// block: 256 thr = 4 waves; block tile 32 rows x 320 cols
// wave w: rows (w>>1)*16, cols (w&1)*160  -> 10 N-tiles of 16, K = 32 + 8(pad)
// A-frags from global (coalesced), W staged bf16 in LDS.
// ---------------------------------------------------------------------------
__global__ __launch_bounds__(256, 3) void biasp_mfma(const float* __restrict__ bias,
                                                     const float* __restrict__ bp_w,
                                                     const float* __restrict__ bp_b,
                                                     float* __restrict__ bias_p,
                                                     float* __restrict__ diffs)
{
    __shared__ unsigned short Wl[HBD * BD];   // [n][k] bf16, 25600 B

    const int t    = threadIdx.x;
    const int w    = t >> 6;
    const int l    = t & 63;
    const int c16  = l & 15;
    const int g    = l >> 4;
    const long row0 = (long)blockIdx.x * 32;

    const int wrow = (w >> 1) * 16;
    const int wcol = (w & 1) * 160;

    // ---- A fragments straight from global (row = row0+wrow+c16) ----
    const long arow = row0 + wrow + c16;
    const float* ap = bias + arow * BD;
    float4 a0 = *(const float4*)(ap + g * 4);          // k = 4g..4g+3
    float4 a1 = *(const float4*)(ap + 16 + g * 4);     // k = 16+4g..
    float4 a2 = make_float4(0.f, 0.f, 0.f, 0.f);
    if (g < 2) a2 = *(const float4*)(ap + 32 + g * 4); // k = 32+4g.. (<40)

    // ---- bp_b columns this lane needs ----
    float bcol[10];
#pragma unroll
    for (int tl = 0; tl < 10; ++tl) bcol[tl] = bp_b[wcol + tl * 16 + c16];

    // ---- stage W as bf16 into LDS ----
    for (int i = t; i < HBD * BD / 4; i += 256) {
        float4 w4 = ((const float4*)bp_w)[i];
        ((uint2*)Wl)[i] = make_uint2((unsigned)f2bf(w4.x) | ((unsigned)f2bf(w4.y) << 16),
                                     (unsigned)f2bf(w4.z) | ((unsigned)f2bf(w4.w) << 16));
    }

    FragU A0, A1;
    A0.u[0] = f2bf(a0.x); A0.u[1] = f2bf(a0.y); A0.u[2] = f2bf(a0.z); A0.u[3] = f2bf(a0.w);
    A0.u[4] = f2bf(a1.x); A0.u[5] = f2bf(a1.y); A0.u[6] = f2bf(a1.z); A0.u[7] = f2bf(a1.w);
    A1.u[0] = f2bf(a2.x); A1.u[1] = f2bf(a2.y); A1.u[2] = f2bf(a2.z); A1.u[3] = f2bf(a2.w);
    A1.d2[1] = make_uint2(0u, 0u);

    __syncthreads();

    // ---- MFMA over 10 N-tiles ----
    f32x4 acc[10];
#pragma unroll
    for (int tl = 0; tl < 10; ++tl) acc[tl] = (f32x4){0.f, 0.f, 0.f, 0.f};

#pragma unroll
    for (int tl = 0; tl < 10; ++tl) {
        const int n = wcol + tl * 16 + c16;
        const uint2* wp = (const uint2*)(Wl + n * BD);   // 8B-aligned (BD*2=80)
        FragU B0, B1;
        B0.d2[0] = wp[g];            // k = 4g..4g+3
        B0.d2[1] = wp[4 + g];        // k = 16+4g..
        B1.d2[0] = (g < 2) ? wp[8 + g] : make_uint2(0u, 0u);  // k = 32+4g (<40)
        B1.d2[1] = make_uint2(0u, 0u);
        acc[tl] = __builtin_amdgcn_mfma_f32_16x16x32_bf16(A0.v, B0.v, acc[tl], 0, 0, 0);
        acc[tl] = __builtin_amdgcn_mfma_f32_16x16x32_bf16(A1.v, B1.v, acc[tl], 0, 0, 0);
    }

    // ---- epilogue: bias add, store, fused ssq for diffs ----
    // D layout: row = g*4 + rr, col = tile*16 + c16
    const long brow = row0 + wrow + g * 4;
    float* pout = bias_p + brow * HBD + wcol + c16;

    float ssq[4][4];
#pragma unroll
    for (int rr = 0; rr < 4; ++rr)
#pragma unroll
        for (int c = 0; c < 4; ++c) ssq[rr][c] = 0.f;

#pragma unroll
    for (int tl = 0; tl < 10; ++tl) {
        const int c_lo = (tl * 16) / BD;                 // chunk of first col
        const int cut  = (c_lo + 1) * BD - tl * 16;      // c16 < cut -> c_lo
#pragma unroll
        for (int rr = 0; rr < 4; ++rr) {
            float x = acc[tl][rr] + bcol[tl];
            pout[rr * HBD + tl * 16] = x;
            float x2 = x * x;
            if (cut >= 16) {
                ssq[rr][c_lo] += x2;
            } else {
                ssq[rr][c_lo]     += (c16 < cut) ? x2 : 0.f;
                ssq[rr][c_lo + 1] += (c16 < cut) ? 0.f : x2;
            }
        }
    }

    // butterfly reduce across the 16 lanes of each g-group
#pragma unroll
    for (int d = 1; d < 16; d <<= 1) {
#pragma unroll
        for (int rr = 0; rr < 4; ++rr)
#pragma unroll
            for (int c = 0; c < 4; ++c)
                ssq[rr][c] += __shfl_xor(ssq[rr][c], d, 16);
    }

    // diffs flat-chunk id q = row*8 + (wcol/40 + c); lane c16==c writes chunk c
#pragma unroll
    for (int c = 0; c < 4; ++c) {
        if (c16 == c) {
#pragma unroll
            for (int rr = 0; rr < 4; ++rr)
                diffs[(brow + rr) * 8 + (w & 1) * 4 + c] = sqrtf(ssq[rr][c]);
        }
    }
}

// ---------------------------------------------------------------------------
// attention (unchanged from round 1)
// ---------------------------------------------------------------------------
__global__ __launch_bounds__(256) void attn_kernel(const float* __restrict__ Qp,
                                                   const float* __restrict__ Kp,
                                                   const float* __restrict__ Vp,
                                                   const float* __restrict__ diffs,
                                                   float* __restrict__ vals)
{
    __shared__ float Ql[16][68];
    __shared__ float KV[64 * 68];
    __shared__ float L[16 * 769];
    __shared__ float red[16][17];
    __shared__ float rowmax[16], rowsuminv[16];

    const int t  = threadIdx.x;
    const int h  = blockIdx.y;
    const int n0 = blockIdx.x * 16;

    for (int idx = t; idx < 16 * 64; idx += 256) {
        int r = idx >> 6, d = idx & 63;
        Ql[r][d] = Qp[(size_t)(n0 + r) * DIM + h * HD + d];
    }

    const int wv  = t >> 6;
    const int mmq = t & 63;

    for (int mt = 0; mt < 12; ++mt) {
        __syncthreads();
        for (int idx = t; idx < 64 * 64; idx += 256) {
            int mm = idx >> 6, d = idx & 63;
            KV[d * 65 + mm] = Kp[(size_t)(mt * 64 + mm) * DIM + h * HD + d];
        }
        __syncthreads();
        float a0 = 0, a1 = 0, a2 = 0, a3 = 0;
#pragma unroll
        for (int d = 0; d < 64; d += 4) {
            float4 q0 = *(const float4*)&Ql[wv][d];
            float4 q1 = *(const float4*)&Ql[wv + 4][d];
            float4 q2 = *(const float4*)&Ql[wv + 8][d];
            float4 q3 = *(const float4*)&Ql[wv + 12][d];
            float k0 = KV[(d    ) * 65 + mmq];
            float k1 = KV[(d + 1) * 65 + mmq];
            float k2 = KV[(d + 2) * 65 + mmq];
            float k3 = KV[(d + 3) * 65 + mmq];
            a0 += q0.x * k0 + q0.y * k1 + q0.z * k2 + q0.w * k3;
            a1 += q1.x * k0 + q1.y * k1 + q1.z * k2 + q1.w * k3;
            a2 += q2.x * k0 + q2.y * k1 + q2.z * k2 + q2.w * k3;
            a3 += q3.x * k0 + q3.y * k1 + q3.z * k2 + q3.w * k3;
        }
        const int m = mt * 64 + mmq;
        const size_t db = (size_t)h * (768 * 768) + (size_t)n0 * 768;
        L[(wv     ) * 769 + m] = a0 * 0.125f + diffs[db + (size_t)(wv     ) * 768 + m];
        L[(wv +  4) * 769 + m] = a1 * 0.125f + diffs[db + (size_t)(wv +  4) * 768 + m];
        L[(wv +  8) * 769 + m] = a2 * 0.125f + diffs[db + (size_t)(wv +  8) * 768 + m];
        L[(wv + 12) * 769 + m] = a3 * 0.125f + diffs[db + (size_t)(wv + 12) * 768 + m];
    }
    __syncthreads();

    {
        const int r = t & 15, seg = t >> 4;
        float mx = -3.4e38f;
        for (int j = 0; j < 48; ++j) mx = fmaxf(mx, L[r * 769 + seg * 48 + j]);
        red[r][seg] = mx;
        __syncthreads();
        if (t < 16) {
            float m = red[t][0];
            for (int s2 = 1; s2 < 16; ++s2) m = fmaxf(m, red[t][s2]);
            rowmax[t] = m;
        }
        __syncthreads();
        const float m = rowmax[r];
        float s = 0.f;
        for (int j = 0; j < 48; ++j) {
            float e = __expf(L[r * 769 + seg * 48 + j] - m);
            L[r * 769 + seg * 48 + j] = e;
            s += e;
        }
        red[r][seg] = s;
        __syncthreads();
        if (t < 16) {
            float sm = 0.f;
            for (int s2 = 0; s2 < 16; ++s2) sm += red[t][s2];
            rowsuminv[t] = 1.f / sm;
        }
    }

    const int r3 = t >> 4, dq = t & 15;
    float4 acc = make_float4(0, 0, 0, 0);
    for (int mt = 0; mt < 12; ++mt) {
        __syncthreads();
        for (int idx = t; idx < 64 * 64; idx += 256) {
            int mm = idx >> 6, d = idx & 63;
            KV[mm * 68 + d] = Vp[(size_t)(mt * 64 + mm) * DIM + h * HD + d];
        }
        __syncthreads();
#pragma unroll 8
        for (int m = 0; m < 64; ++m) {
            float p = L[r3 * 769 + mt * 64 + m];
            float4 vv = *(const float4*)&KV[m * 68 + dq * 4];
            acc.x += p * vv.x; acc.y += p * vv.y;
            acc.z += p * vv.z; acc.w += p * vv.w;
        }
    }
    const float inv = rowsuminv[r3];
    acc.x *= inv; acc.y *= inv; acc.z *= inv; acc.w *= inv;
    *(float4*)&vals[(size_t)(n0 + r3) * DIM + h * HD + dq * 4] = acc;
}

// ---------------------------------------------------------------------------
extern "C" void kernel_launch(void* const* d_in, const int* in_sizes, int n_in,
                              void* d_out, int out_size, void* d_ws, size_t ws_size,
                              hipStream_t stream)
{
    const float* q    = (const float*)d_in[0];
    const float* k    = (const float*)d_in[1];
    const float* v    = (const float*)d_in[2];
    const float* bias = (const float*)d_in[3];
    const float* q_w  = (const float*)d_in[4];
    const float* q_b  = (const float*)d_in[5];
    const float* k_w  = (const float*)d_in[6];
    const float* k_b  = (const float*)d_in[7];
    const float* v_w  = (const float*)d_in[8];
    const float* v_b  = (const float*)d_in[9];
    const float* bp_w = (const float*)d_in[10];
    const float* bp_b = (const float*)d_in[11];
    const float* o1_w = (const float*)d_in[12];
    const float* o1_b = (const float*)d_in[13];
    const float* o2_w = (const float*)d_in[14];
    const float* o2_b = (const float*)d_in[15];

    float* out    = (float*)d_out;                 // [768][512]
    float* bias_p = (float*)d_out + 393216;        // [589824][320]

    float* ws    = (float*)d_ws;
    float* Qp    = ws;                 // 768*512
    float* Kp    = ws + 393216;
    float* Vp    = ws + 786432;
    float* vals  = ws + 1179648;
    float* mid   = ws + 1572864;
    float* diffs = ws + 1966080;       // 8*768*768

    dim3 gg(12, 8), gb(256);
    gemm_tn<<<gg, gb, 0, stream>>>(q, q_w, q_b, Qp, 0);
    gemm_tn<<<gg, gb, 0, stream>>>(k, k_w, k_b, Kp, 0);
    gemm_tn<<<gg, gb, 0, stream>>>(v, v_w, v_b, Vp, 0);
    biasp_mfma<<<dim3(NROWS / 32), gb, 0, stream>>>(bias, bp_w, bp_b, bias_p, diffs);
    attn_kernel<<<dim3(48, NH), gb, 0, stream>>>(Qp, Kp, Vp, diffs, vals);
    gemm_tn<<<gg, gb, 0, stream>>>(vals, o1_w, o1_b, mid, 1);
    gemm_tn<<<gg, gb, 0, stream>>>(mid, o2_w, o2_b, out, 0);
}

// Round 5
// 475.643 us; speedup vs baseline: 1.4910x; 1.0321x over previous
//
#include <hip/hip_runtime.h>
#include <math.h>

#define NS   768
#define DIM  512
#define NH   8
#define HD   64
#define BD   40
#define HBD  320
#define NROWS (768*768)

typedef __bf16 bf16x8 __attribute__((ext_vector_type(8)));
typedef float  f32x4  __attribute__((ext_vector_type(4)));

union FragU {
    bf16x8 v;
    unsigned short u[8];
    uint2 d2[2];
};

__device__ inline unsigned short f2bf(float f) {
    unsigned int u = __float_as_uint(f);
    unsigned int r = (u + 0x7fffu + ((u >> 16) & 1u)) >> 16;
    return (unsigned short)r;
}
__device__ inline unsigned int pk2(float x, float y) {
    return (unsigned)f2bf(x) | ((unsigned)f2bf(y) << 16);
}

// ---------------------------------------------------------------------------
// MFMA GEMM: C[768][512] = A[768][512] @ W[512][512]^T + b, optional mish.
// block 256 = 4 waves; tile 64x64; wave w: rows w*16, 4 N-tiles of 16.
// swapped operands: a=W-frag (M=cols), b=A-frag (N=rows) -> lane holds 4
// consecutive output cols -> float4 stores.
// ---------------------------------------------------------------------------
__global__ __launch_bounds__(256) void gemm_mfma(const float* __restrict__ A,
                                                 const float* __restrict__ W,
                                                 const float* __restrict__ bvec,
                                                 float* __restrict__ C,
                                                 int act)
{
    __shared__ unsigned short As[64][72];   // [row][k] bf16, pad to 72
    __shared__ unsigned short Ws[64][72];   // [col][k] bf16

    const int t   = threadIdx.x;
    const int w   = t >> 6;
    const int l   = t & 63;
    const int c16 = l & 15;
    const int g   = l >> 4;
    const int m0  = blockIdx.x * 64;
    const int cb  = blockIdx.y * 64;

    f32x4 acc[4];
#pragma unroll
    for (int tl = 0; tl < 4; ++tl) acc[tl] = (f32x4){0.f, 0.f, 0.f, 0.f};

    for (int kc = 0; kc < DIM; kc += 64) {
        __syncthreads();
#pragma unroll
        for (int rep = 0; rep < 4; ++rep) {
            int f   = t + rep * 256;        // float4 id 0..1023
            int row = f >> 4;
            int kk  = (f & 15) << 2;
            float4 a4 = *(const float4*)&A[(size_t)(m0 + row) * DIM + kc + kk];
            *(uint2*)&As[row][kk] = make_uint2(pk2(a4.x, a4.y), pk2(a4.z, a4.w));
            float4 w4 = *(const float4*)&W[(size_t)(cb + row) * DIM + kc + kk];
            *(uint2*)&Ws[row][kk] = make_uint2(pk2(w4.x, w4.y), pk2(w4.z, w4.w));
        }
        __syncthreads();
#pragma unroll
        for (int ks = 0; ks < 2; ++ks) {
            const int k0 = ks * 32;
            FragU bA;
            bA.d2[0] = *(const uint2*)&As[w * 16 + c16][k0 + 4 * g];
            bA.d2[1] = *(const uint2*)&As[w * 16 + c16][k0 + 16 + 4 * g];
#pragma unroll
            for (int tl = 0; tl < 4; ++tl) {
                FragU aW;
                aW.d2[0] = *(const uint2*)&Ws[tl * 16 + c16][k0 + 4 * g];
                aW.d2[1] = *(const uint2*)&Ws[tl * 16 + c16][k0 + 16 + 4 * g];
                acc[tl] = __builtin_amdgcn_mfma_f32_16x16x32_bf16(aW.v, bA.v, acc[tl], 0, 0, 0);
            }
        }
    }

    const int row = m0 + w * 16 + c16;
#pragma unroll
    for (int tl = 0; tl < 4; ++tl) {
        const int col = cb + tl * 16 + g * 4;
        float4 bb = *(const float4*)&bvec[col];
        float o[4] = {acc[tl][0] + bb.x, acc[tl][1] + bb.y,
                      acc[tl][2] + bb.z, acc[tl][3] + bb.w};
        if (act) {
#pragma unroll
            for (int rr = 0; rr < 4; ++rr)
                o[rr] = o[rr] * tanhf(log1pf(expf(o[rr])));
        }
        *(float4*)&C[(size_t)row * DIM + col] =
            make_float4(o[0], o[1], o[2], o[3]);
    }
}

// ---------------------------------------------------------------------------
// biasp via MFMA bf16 (swapped operands):
//   bias_p[r][c] = sum_k bias[r][k]*bp_w[c][k] + bp_b[c]; diffs = 40-chunk L2.
// block 512 thr = 8 waves, 64 rows; wave w: rows (w>>1)*16, cols (w&1)*160.
// D layout: lane holds cols g*4..g*4+3 of row c16 -> float4 stores.
// ---------------------------------------------------------------------------
__global__ __launch_bounds__(512) void biasp_mfma(const float* __restrict__ bias,
                                                  const float* __restrict__ bp_w,
                                                  const float* __restrict__ bp_b,
                                                  float* __restrict__ bias_p,
                                                  float* __restrict__ diffs)
{
    __shared__ unsigned short Wl[HBD * BD];   // [n][k] bf16, 25600 B

    const int t    = threadIdx.x;
    const int w    = t >> 6;
    const int l    = t & 63;
    const int c16  = l & 15;
    const int g    = l >> 4;
    const long row0 = (long)blockIdx.x * 64;

    const int wrow = (w >> 1) * 16;
    const int wcol = (w & 1) * 160;

    // A (bias) fragments straight from global; becomes the *b* operand
    const long arow = row0 + wrow + c16;
    const float* ap = bias + arow * BD;
    float4 a0 = *(const float4*)(ap + g * 4);
    float4 a1 = *(const float4*)(ap + 16 + g * 4);
    float4 a2 = make_float4(0.f, 0.f, 0.f, 0.f);
    if (g < 2) a2 = *(const float4*)(ap + 32 + g * 4);

    // stage W as bf16 into LDS
    for (int i = t; i < HBD * BD / 4; i += 512) {
        float4 w4 = ((const float4*)bp_w)[i];
        ((uint2*)Wl)[i] = make_uint2(pk2(w4.x, w4.y), pk2(w4.z, w4.w));
    }

    FragU A0, A1;
    A0.d2[0] = make_uint2(pk2(a0.x, a0.y), pk2(a0.z, a0.w));
    A0.d2[1] = make_uint2(pk2(a1.x, a1.y), pk2(a1.z, a1.w));
    A1.d2[0] = make_uint2(pk2(a2.x, a2.y), pk2(a2.z, a2.w));
    A1.d2[1] = make_uint2(0u, 0u);

    __syncthreads();

    f32x4 acc[10];
#pragma unroll
    for (int tl = 0; tl < 10; ++tl) acc[tl] = (f32x4){0.f, 0.f, 0.f, 0.f};

#pragma unroll
    for (int tl = 0; tl < 10; ++tl) {
        const int n = wcol + tl * 16 + c16;           // W col this lane supplies
        const uint2* wp = (const uint2*)(Wl + n * BD);
        FragU B0, B1;
        B0.d2[0] = wp[g];
        B0.d2[1] = wp[4 + g];
        B1.d2[0] = (g < 2) ? wp[8 + g] : make_uint2(0u, 0u);
        B1.d2[1] = make_uint2(0u, 0u);
        // swapped: a = W (M=cols), b = bias (N=rows)
        acc[tl] = __builtin_amdgcn_mfma_f32_16x16x32_bf16(B0.v, A0.v, acc[tl], 0, 0, 0);
        acc[tl] = __builtin_amdgcn_mfma_f32_16x16x32_bf16(B1.v, A1.v, acc[tl], 0, 0, 0);
    }

    // epilogue: lane owns row (row0+wrow+c16), cols wcol + tl*16 + g*4 .. +3
    const long brow = row0 + wrow + c16;
    float* pout = bias_p + brow * HBD + wcol;

    float ssq[4] = {0.f, 0.f, 0.f, 0.f};
#pragma unroll
    for (int tl = 0; tl < 10; ++tl) {
        const int cbase = tl * 16 + g * 4;            // 0..156, runtime (g)
        float4 bb = *(const float4*)&bp_b[wcol + cbase];
        float x0 = acc[tl][0] + bb.x;
        float x1 = acc[tl][1] + bb.y;
        float x2 = acc[tl][2] + bb.z;
        float x3 = acc[tl][3] + bb.w;
        *(float4*)&pout[cbase] = make_float4(x0, x1, x2, x3);
        float s = x0 * x0 + x1 * x1 + x2 * x2 + x3 * x3;
        // local chunk = cbase/40 (4-col group never straddles: 40 % 4 == 0)
        ssq[0] += (cbase < 40) ? s : 0.f;
        ssq[1] += (cbase >= 40 && cbase < 80) ? s : 0.f;
        ssq[2] += (cbase >= 80 && cbase < 120) ? s : 0.f;
        ssq[3] += (cbase >= 120) ? s : 0.f;
    }

    // sum across the 4 g-groups holding the same row (lanes differ in bits 4,5)
#pragma unroll
    for (int c = 0; c < 4; ++c) {
        ssq[c] += __shfl_xor(ssq[c], 16);
        ssq[c] += __shfl_xor(ssq[c], 32);
    }
    float v = (g == 0) ? ssq[0] : (g == 1) ? ssq[1] : (g == 2) ? ssq[2] : ssq[3];
    diffs[brow * 8 + (w & 1) * 4 + g] = sqrtf(v);
}

// ---------------------------------------------------------------------------
// attention (unchanged)
// ---------------------------------------------------------------------------
__global__ __launch_bounds__(256) void attn_kernel(const float* __restrict__ Qp,
                                                   const float* __restrict__ Kp,
                                                   const float* __restrict__ Vp,
                                                   const float* __restrict__ diffs,
                                                   float* __restrict__ vals)
{
    __shared__ float Ql[16][68];
    __shared__ float KV[64 * 68];
    __shared__ float L[16 * 769];
    __shared__ float red[16][17];
    __shared__ float rowmax[16], rowsuminv[16];

    const int t  = threadIdx.x;
    const int h  = blockIdx.y;
    const int n0 = blockIdx.x * 16;

    for (int idx = t; idx < 16 * 64; idx += 256) {
        int r = idx >> 6, d = idx & 63;
        Ql[r][d] = Qp[(size_t)(n0 + r) * DIM + h * HD + d];
    }

    const int wv  = t >> 6;
    const int mmq = t & 63;

    for (int mt = 0; mt < 12; ++mt) {
        __syncthreads();
        for (int idx = t; idx < 64 * 64; idx += 256) {
            int mm = idx >> 6, d = idx & 63;
            KV[d * 65 + mm] = Kp[(size_t)(mt * 64 + mm) * DIM + h * HD + d];
        }
        __syncthreads();
        float a0 = 0, a1 = 0, a2 = 0, a3 = 0;
#pragma unroll
        for (int d = 0; d < 64; d += 4) {
            float4 q0 = *(const float4*)&Ql[wv][d];
            float4 q1 = *(const float4*)&Ql[wv + 4][d];
            float4 q2 = *(const float4*)&Ql[wv + 8][d];
            float4 q3 = *(const float4*)&Ql[wv + 12][d];
            float k0 = KV[(d    ) * 65 + mmq];
            float k1 = KV[(d + 1) * 65 + mmq];
            float k2 = KV[(d + 2) * 65 + mmq];
            float k3 = KV[(d + 3) * 65 + mmq];
            a0 += q0.x * k0 + q0.y * k1 + q0.z * k2 + q0.w * k3;
            a1 += q1.x * k0 + q1.y * k1 + q1.z * k2 + q1.w * k3;
            a2 += q2.x * k0 + q2.y * k1 + q2.z * k2 + q2.w * k3;
            a3 += q3.x * k0 + q3.y * k1 + q3.z * k2 + q3.w * k3;
        }
        const int m = mt * 64 + mmq;
        const size_t db = (size_t)h * (768 * 768) + (size_t)n0 * 768;
        L[(wv     ) * 769 + m] = a0 * 0.125f + diffs[db + (size_t)(wv     ) * 768 + m];
        L[(wv +  4) * 769 + m] = a1 * 0.125f + diffs[db + (size_t)(wv +  4) * 768 + m];
        L[(wv +  8) * 769 + m] = a2 * 0.125f + diffs[db + (size_t)(wv +  8) * 768 + m];
        L[(wv + 12) * 769 + m] = a3 * 0.125f + diffs[db + (size_t)(wv + 12) * 768 + m];
    }
    __syncthreads();

    {
        const int r = t & 15, seg = t >> 4;
        float mx = -3.4e38f;
        for (int j = 0; j < 48; ++j) mx = fmaxf(mx, L[r * 769 + seg * 48 + j]);
        red[r][seg] = mx;
        __syncthreads();
        if (t < 16) {
            float m = red[t][0];
            for (int s2 = 1; s2 < 16; ++s2) m = fmaxf(m, red[t][s2]);
            rowmax[t] = m;
        }
        __syncthreads();
        const float m = rowmax[r];
        float s = 0.f;
        for (int j = 0; j < 48; ++j) {
            float e = __expf(L[r * 769 + seg * 48 + j] - m);
            L[r * 769 + seg * 48 + j] = e;
            s += e;
        }
        red[r][seg] = s;
        __syncthreads();
        if (t < 16) {
            float sm = 0.f;
            for (int s2 = 0; s2 < 16; ++s2) sm += red[t][s2];
            rowsuminv[t] = 1.f / sm;
        }
    }

    const int r3 = t >> 4, dq = t & 15;
    float4 acc = make_float4(0, 0, 0, 0);
    for (int mt = 0; mt < 12; ++mt) {
        __syncthreads();
        for (int idx = t; idx < 64 * 64; idx += 256) {
            int mm = idx >> 6, d = idx & 63;
            KV[mm * 68 + d] = Vp[(size_t)(mt * 64 + mm) * DIM + h * HD + d];
        }
        __syncthreads();
#pragma unroll 8
        for (int m = 0; m < 64; ++m) {
            float p = L[r3 * 769 + mt * 64 + m];
            float4 vv = *(const float4*)&KV[m * 68 + dq * 4];
            acc.x += p * vv.x; acc.y += p * vv.y;
            acc.z += p * vv.z; acc.w += p * vv.w;
        }
    }
    const float inv = rowsuminv[r3];
    acc.x *= inv; acc.y *= inv; acc.z *= inv; acc.w *= inv;
    *(float4*)&vals[(size_t)(n0 + r3) * DIM + h * HD + dq * 4] = acc;
}

// ---------------------------------------------------------------------------
extern "C" void kernel_launch(void* const* d_in, const int* in_sizes, int n_in,
                              void* d_out, int out_size, void* d_ws, size_t ws_size,
                              hipStream_t stream)
{
    const float* q    = (const float*)d_in[0];
    const float* k    = (const float*)d_in[1];
    const float* v    = (const float*)d_in[2];
    const float* bias = (const float*)d_in[3];
    const float* q_w  = (const float*)d_in[4];
    const float* q_b  = (const float*)d_in[5];
    const float* k_w  = (const float*)d_in[6];
    const float* k_b  = (const float*)d_in[7];
    const float* v_w  = (const float*)d_in[8];
    const float* v_b  = (const float*)d_in[9];
    const float* bp_w = (const float*)d_in[10];
    const float* bp_b = (const float*)d_in[11];
    const float* o1_w = (const float*)d_in[12];
    const float* o1_b = (const float*)d_in[13];
    const float* o2_w = (const float*)d_in[14];
    const float* o2_b = (const float*)d_in[15];

    float* out    = (float*)d_out;                 // [768][512]
    float* bias_p = (float*)d_out + 393216;        // [589824][320]

    float* ws    = (float*)d_ws;
    float* Qp    = ws;                 // 768*512
    float* Kp    = ws + 393216;
    float* Vp    = ws + 786432;
    float* vals  = ws + 1179648;
    float* mid   = ws + 1572864;
    float* diffs = ws + 1966080;       // 8*768*768

    dim3 gg(12, 8), gb(256);
    gemm_mfma<<<gg, gb, 0, stream>>>(q, q_w, q_b, Qp, 0);
    gemm_mfma<<<gg, gb, 0, stream>>>(k, k_w, k_b, Kp, 0);
    gemm_mfma<<<gg, gb, 0, stream>>>(v, v_w, v_b, Vp, 0);
    biasp_mfma<<<dim3(NROWS / 64), dim3(512), 0, stream>>>(bias, bp_w, bp_b, bias_p, diffs);
    attn_kernel<<<dim3(48, NH), gb, 0, stream>>>(Qp, Kp, Vp, diffs, vals);
    gemm_mfma<<<gg, gb, 0, stream>>>(vals, o1_w, o1_b, mid, 1);
    gemm_mfma<<<gg, gb, 0, stream>>>(mid, o2_w, o2_b, out, 0);
}

// Round 7
// 385.820 us; speedup vs baseline: 1.8381x; 1.2328x over previous
//
#include <hip/hip_runtime.h>
#include <math.h>

#define NS   768
#define DIM  512
#define NH   8
#define HD   64
#define BD   40
#define HBD  320
#define NROWS (768*768)

typedef __bf16 bf16x8 __attribute__((ext_vector_type(8)));
typedef float  f32x4  __attribute__((ext_vector_type(4)));

union FragU {
    bf16x8 v;
    unsigned short u[8];
    uint2 d2[2];
};

__device__ inline unsigned short f2bf(float f) {
    unsigned int u = __float_as_uint(f);
    unsigned int r = (u + 0x7fffu + ((u >> 16) & 1u)) >> 16;
    return (unsigned short)r;
}
__device__ inline unsigned int pk2(float x, float y) {
    return (unsigned)f2bf(x) | ((unsigned)f2bf(y) << 16);
}

// ---------------------------------------------------------------------------
// MFMA GEMM: C[768][512] = A[768][512] @ W[512][512]^T + b, optional mish.
// ---------------------------------------------------------------------------
__global__ __launch_bounds__(256) void gemm_mfma(const float* __restrict__ A,
                                                 const float* __restrict__ W,
                                                 const float* __restrict__ bvec,
                                                 float* __restrict__ C,
                                                 int act)
{
    __shared__ unsigned short As[64][72];   // [row][k] bf16, pad to 72
    __shared__ unsigned short Ws[64][72];   // [col][k] bf16

    const int t   = threadIdx.x;
    const int w   = t >> 6;
    const int l   = t & 63;
    const int c16 = l & 15;
    const int g   = l >> 4;
    const int m0  = blockIdx.x * 64;
    const int cb  = blockIdx.y * 64;

    f32x4 acc[4];
#pragma unroll
    for (int tl = 0; tl < 4; ++tl) acc[tl] = (f32x4){0.f, 0.f, 0.f, 0.f};

    for (int kc = 0; kc < DIM; kc += 64) {
        __syncthreads();
#pragma unroll
        for (int rep = 0; rep < 4; ++rep) {
            int f   = t + rep * 256;        // float4 id 0..1023
            int row = f >> 4;
            int kk  = (f & 15) << 2;
            float4 a4 = *(const float4*)&A[(size_t)(m0 + row) * DIM + kc + kk];
            *(uint2*)&As[row][kk] = make_uint2(pk2(a4.x, a4.y), pk2(a4.z, a4.w));
            float4 w4 = *(const float4*)&W[(size_t)(cb + row) * DIM + kc + kk];
            *(uint2*)&Ws[row][kk] = make_uint2(pk2(w4.x, w4.y), pk2(w4.z, w4.w));
        }
        __syncthreads();
#pragma unroll
        for (int ks = 0; ks < 2; ++ks) {
            const int k0 = ks * 32;
            FragU bA;
            bA.d2[0] = *(const uint2*)&As[w * 16 + c16][k0 + 4 * g];
            bA.d2[1] = *(const uint2*)&As[w * 16 + c16][k0 + 16 + 4 * g];
#pragma unroll
            for (int tl = 0; tl < 4; ++tl) {
                FragU aW;
                aW.d2[0] = *(const uint2*)&Ws[tl * 16 + c16][k0 + 4 * g];
                aW.d2[1] = *(const uint2*)&Ws[tl * 16 + c16][k0 + 16 + 4 * g];
                acc[tl] = __builtin_amdgcn_mfma_f32_16x16x32_bf16(aW.v, bA.v, acc[tl], 0, 0, 0);
            }
        }
    }

    const int row = m0 + w * 16 + c16;
#pragma unroll
    for (int tl = 0; tl < 4; ++tl) {
        const int col = cb + tl * 16 + g * 4;
        float4 bb = *(const float4*)&bvec[col];
        float o[4] = {acc[tl][0] + bb.x, acc[tl][1] + bb.y,
                      acc[tl][2] + bb.z, acc[tl][3] + bb.w};
        if (act) {
#pragma unroll
            for (int rr = 0; rr < 4; ++rr)
                o[rr] = o[rr] * tanhf(log1pf(expf(o[rr])));
        }
        *(float4*)&C[(size_t)row * DIM + col] =
            make_float4(o[0], o[1], o[2], o[3]);
    }
}

// ---------------------------------------------------------------------------
// biasp via MFMA bf16 (swapped operands) + nontemporal bias_p stores.
// ---------------------------------------------------------------------------
__global__ __launch_bounds__(512) void biasp_mfma(const float* __restrict__ bias,
                                                  const float* __restrict__ bp_w,
                                                  const float* __restrict__ bp_b,
                                                  float* __restrict__ bias_p,
                                                  float* __restrict__ diffs)
{
    __shared__ unsigned short Wl[HBD * BD];   // [n][k] bf16, 25600 B

    const int t    = threadIdx.x;
    const int w    = t >> 6;
    const int l    = t & 63;
    const int c16  = l & 15;
    const int g    = l >> 4;
    const long row0 = (long)blockIdx.x * 64;

    const int wrow = (w >> 1) * 16;
    const int wcol = (w & 1) * 160;

    const long arow = row0 + wrow + c16;
    const float* ap = bias + arow * BD;
    float4 a0 = *(const float4*)(ap + g * 4);
    float4 a1 = *(const float4*)(ap + 16 + g * 4);
    float4 a2 = make_float4(0.f, 0.f, 0.f, 0.f);
    if (g < 2) a2 = *(const float4*)(ap + 32 + g * 4);

    for (int i = t; i < HBD * BD / 4; i += 512) {
        float4 w4 = ((const float4*)bp_w)[i];
        ((uint2*)Wl)[i] = make_uint2(pk2(w4.x, w4.y), pk2(w4.z, w4.w));
    }

    FragU A0, A1;
    A0.d2[0] = make_uint2(pk2(a0.x, a0.y), pk2(a0.z, a0.w));
    A0.d2[1] = make_uint2(pk2(a1.x, a1.y), pk2(a1.z, a1.w));
    A1.d2[0] = make_uint2(pk2(a2.x, a2.y), pk2(a2.z, a2.w));
    A1.d2[1] = make_uint2(0u, 0u);

    __syncthreads();

    f32x4 acc[10];
#pragma unroll
    for (int tl = 0; tl < 10; ++tl) acc[tl] = (f32x4){0.f, 0.f, 0.f, 0.f};

#pragma unroll
    for (int tl = 0; tl < 10; ++tl) {
        const int n = wcol + tl * 16 + c16;
        const uint2* wp = (const uint2*)(Wl + n * BD);
        FragU B0, B1;
        B0.d2[0] = wp[g];
        B0.d2[1] = wp[4 + g];
        B1.d2[0] = (g < 2) ? wp[8 + g] : make_uint2(0u, 0u);
        B1.d2[1] = make_uint2(0u, 0u);
        acc[tl] = __builtin_amdgcn_mfma_f32_16x16x32_bf16(B0.v, A0.v, acc[tl], 0, 0, 0);
        acc[tl] = __builtin_amdgcn_mfma_f32_16x16x32_bf16(B1.v, A1.v, acc[tl], 0, 0, 0);
    }

    const long brow = row0 + wrow + c16;
    float* pout = bias_p + brow * HBD + wcol;

    float ssq[4] = {0.f, 0.f, 0.f, 0.f};
#pragma unroll
    for (int tl = 0; tl < 10; ++tl) {
        const int cbase = tl * 16 + g * 4;
        float4 bb = *(const float4*)&bp_b[wcol + cbase];
        float x0 = acc[tl][0] + bb.x;
        float x1 = acc[tl][1] + bb.y;
        float x2 = acc[tl][2] + bb.z;
        float x3 = acc[tl][3] + bb.w;
        f32x4 sv = {x0, x1, x2, x3};
        __builtin_nontemporal_store(sv, (f32x4*)&pout[cbase]);
        float s = x0 * x0 + x1 * x1 + x2 * x2 + x3 * x3;
        ssq[0] += (cbase < 40) ? s : 0.f;
        ssq[1] += (cbase >= 40 && cbase < 80) ? s : 0.f;
        ssq[2] += (cbase >= 80 && cbase < 120) ? s : 0.f;
        ssq[3] += (cbase >= 120) ? s : 0.f;
    }

#pragma unroll
    for (int c = 0; c < 4; ++c) {
        ssq[c] += __shfl_xor(ssq[c], 16);
        ssq[c] += __shfl_xor(ssq[c], 32);
    }
    float v = (g == 0) ? ssq[0] : (g == 1) ? ssq[1] : (g == 2) ? ssq[2] : ssq[3];
    diffs[brow * 8 + (w & 1) * 4 + g] = sqrtf(v);
}

// ---------------------------------------------------------------------------
// attn via MFMA, flash-style. Block = 256 thr = 4 waves, 16 q-rows per block.
// Wave wv handles keys [wv*192, wv*192+192) with online softmax; LDS merge.
// S^T trick: S = mfma(K,Q) puts P in the A-frag layout for PV (q = lane&15).
// ---------------------------------------------------------------------------
__global__ __launch_bounds__(256) void attn_mfma(const float* __restrict__ Qp,
                                                 const float* __restrict__ Kp,
                                                 const float* __restrict__ Vp,
                                                 const float* __restrict__ diffs,
                                                 float* __restrict__ vals)
{
    __shared__ float Lacc[4][64][17];
    __shared__ float Lm[4][16];
    __shared__ float Ll[4][16];

    const int t   = threadIdx.x;
    const int wv  = t >> 6;
    const int l   = t & 63;
    const int c16 = l & 15;
    const int g   = l >> 4;
    const int h   = blockIdx.y;
    const int n0  = blockIdx.x * 16;

    // Q fragments (B operand): q-row = n0 + c16
    const float* qrow = Qp + (size_t)(n0 + c16) * DIM + h * HD;
    FragU Qf[2];
#pragma unroll
    for (int kh = 0; kh < 2; ++kh) {
        float4 x0 = *(const float4*)(qrow + 4 * g + 32 * kh);
        float4 x1 = *(const float4*)(qrow + 16 + 4 * g + 32 * kh);
        Qf[kh].d2[0] = make_uint2(pk2(x0.x, x0.y), pk2(x0.z, x0.w));
        Qf[kh].d2[1] = make_uint2(pk2(x1.x, x1.y), pk2(x1.z, x1.w));
    }

    float m_run = -1e30f, l_run = 0.f;
    f32x4 acc[4];
#pragma unroll
    for (int dt = 0; dt < 4; ++dt) acc[dt] = (f32x4){0.f, 0.f, 0.f, 0.f};

    for (int ti = 0; ti < 3; ++ti) {
        const int kb = (wv * 3 + ti) * 64;

        // ---- S^T = K . Q^T : lane holds S[key = kb+kt*16+4g+r][q = n0+c16] ----
        f32x4 s[4];
#pragma unroll
        for (int kt = 0; kt < 4; ++kt) s[kt] = (f32x4){0.f, 0.f, 0.f, 0.f};
#pragma unroll
        for (int kh = 0; kh < 2; ++kh) {
#pragma unroll
            for (int kt = 0; kt < 4; ++kt) {
                const float* krow = Kp + (size_t)(kb + kt * 16 + c16) * DIM + h * HD;
                float4 x0 = *(const float4*)(krow + 4 * g + 32 * kh);
                float4 x1 = *(const float4*)(krow + 16 + 4 * g + 32 * kh);
                FragU Kf;
                Kf.d2[0] = make_uint2(pk2(x0.x, x0.y), pk2(x0.z, x0.w));
                Kf.d2[1] = make_uint2(pk2(x1.x, x1.y), pk2(x1.z, x1.w));
                s[kt] = __builtin_amdgcn_mfma_f32_16x16x32_bf16(Kf.v, Qf[kh].v, s[kt], 0, 0, 0);
            }
        }

        // ---- scale + diffs, tile max ----
        const float* dbase = diffs + (size_t)h * 589824 + (size_t)(n0 + c16) * 768 + kb;
        float mx = -1e30f;
#pragma unroll
        for (int kt = 0; kt < 4; ++kt) {
            float4 d4 = *(const float4*)(dbase + kt * 16 + 4 * g);
            float dd[4] = {d4.x, d4.y, d4.z, d4.w};
#pragma unroll
            for (int r = 0; r < 4; ++r) {
                float x = s[kt][r] * 0.125f + dd[r];
                s[kt][r] = x;
                mx = fmaxf(mx, x);
            }
        }
        mx = fmaxf(mx, __shfl_xor(mx, 16));
        mx = fmaxf(mx, __shfl_xor(mx, 32));
        const float m_new = fmaxf(m_run, mx);
        const float scale = __expf(m_run - m_new);

        float psum = 0.f;
#pragma unroll
        for (int kt = 0; kt < 4; ++kt)
#pragma unroll
            for (int r = 0; r < 4; ++r) {
                float e = __expf(s[kt][r] - m_new);
                s[kt][r] = e;
                psum += e;
            }
        psum += __shfl_xor(psum, 16);
        psum += __shfl_xor(psum, 32);
        l_run = l_run * scale + psum;
        m_run = m_new;
#pragma unroll
        for (int dt = 0; dt < 4; ++dt)
#pragma unroll
            for (int r = 0; r < 4; ++r) acc[dt][r] *= scale;

        // ---- pack P as A-frags (q = lane&15 matches) ----
        FragU Pf[2];
#pragma unroll
        for (int kh = 0; kh < 2; ++kh)
#pragma unroll
            for (int j = 0; j < 8; ++j)
                Pf[kh].u[j] = f2bf(s[2 * kh + (j >> 2)][j & 3]);

        // ---- PV: acc[dt] += P . V  (V as B operand, scalar coalesced loads) ----
#pragma unroll
        for (int kh = 0; kh < 2; ++kh) {
#pragma unroll
            for (int dt = 0; dt < 4; ++dt) {
                FragU Vf;
#pragma unroll
                for (int j = 0; j < 8; ++j) {
                    Vf.u[j] = f2bf(Vp[(size_t)(kb + 32 * kh + 4 * g + (j & 3) + 16 * (j >> 2)) * DIM
                                      + h * HD + dt * 16 + c16]);
                }
                acc[dt] = __builtin_amdgcn_mfma_f32_16x16x32_bf16(Pf[kh].v, Vf.v, acc[dt], 0, 0, 0);
            }
        }
    }

    // ---- cross-wave merge via LDS ----
#pragma unroll
    for (int dt = 0; dt < 4; ++dt)
#pragma unroll
        for (int r = 0; r < 4; ++r) Lacc[wv][l][dt * 4 + r] = acc[dt][r];
    if (g == 0) { Lm[wv][c16] = m_run; Ll[wv][c16] = l_run; }
    __syncthreads();

    // this wave finalizes d-quadrant dt = wv; element q = 4g + r, d = wv*16 + c16
#pragma unroll
    for (int r = 0; r < 4; ++r) {
        const int qr = 4 * g + r;
        float M = fmaxf(fmaxf(Lm[0][qr], Lm[1][qr]), fmaxf(Lm[2][qr], Lm[3][qr]));
        float Lsum = 0.f, a = 0.f;
#pragma unroll
        for (int w2 = 0; w2 < 4; ++w2) {
            float e = __expf(Lm[w2][qr] - M);
            Lsum += Ll[w2][qr] * e;
            a += Lacc[w2][l][wv * 4 + r] * e;
        }
        vals[(size_t)(n0 + qr) * DIM + h * HD + wv * 16 + c16] = a / Lsum;
    }
}

// ---------------------------------------------------------------------------
extern "C" void kernel_launch(void* const* d_in, const int* in_sizes, int n_in,
                              void* d_out, int out_size, void* d_ws, size_t ws_size,
                              hipStream_t stream)
{
    const float* q    = (const float*)d_in[0];
    const float* k    = (const float*)d_in[1];
    const float* v    = (const float*)d_in[2];
    const float* bias = (const float*)d_in[3];
    const float* q_w  = (const float*)d_in[4];
    const float* q_b  = (const float*)d_in[5];
    const float* k_w  = (const float*)d_in[6];
    const float* k_b  = (const float*)d_in[7];
    const float* v_w  = (const float*)d_in[8];
    const float* v_b  = (const float*)d_in[9];
    const float* bp_w = (const float*)d_in[10];
    const float* bp_b = (const float*)d_in[11];
    const float* o1_w = (const float*)d_in[12];
    const float* o1_b = (const float*)d_in[13];
    const float* o2_w = (const float*)d_in[14];
    const float* o2_b = (const float*)d_in[15];

    float* out    = (float*)d_out;                 // [768][512]
    float* bias_p = (float*)d_out + 393216;        // [589824][320]

    float* ws    = (float*)d_ws;
    float* Qp    = ws;                 // 768*512
    float* Kp    = ws + 393216;
    float* Vp    = ws + 786432;
    float* vals  = ws + 1179648;
    float* mid   = ws + 1572864;
    float* diffs = ws + 1966080;       // 8*768*768

    dim3 gg(12, 8), gb(256);
    gemm_mfma<<<gg, gb, 0, stream>>>(q, q_w, q_b, Qp, 0);
    gemm_mfma<<<gg, gb, 0, stream>>>(k, k_w, k_b, Kp, 0);
    gemm_mfma<<<gg, gb, 0, stream>>>(v, v_w, v_b, Vp, 0);
    biasp_mfma<<<dim3(NROWS / 64), dim3(512), 0, stream>>>(bias, bp_w, bp_b, bias_p, diffs);
    attn_mfma<<<dim3(48, NH), gb, 0, stream>>>(Qp, Kp, Vp, diffs, vals);
    gemm_mfma<<<gg, gb, 0, stream>>>(vals, o1_w, o1_b, mid, 1);
    gemm_mfma<<<gg, gb, 0, stream>>>(mid, o2_w, o2_b, out, 0);
}